// Round 8
// baseline (1104.809 us; speedup 1.0000x reference)
//
#include <hip/hip_runtime.h>

#define Hc 256
#define Dc 64
#define Tc 49
#define Bc 4800
#define NPc 16384
#define KOUT 12544          // T*H
#define OUTSTRIDE 1228800   // 4800*256

typedef unsigned short u16;
typedef unsigned int u32;
typedef __bf16 bf16x8 __attribute__((ext_vector_type(8)));
typedef float f32x4 __attribute__((ext_vector_type(4)));

__device__ __forceinline__ u16 f2bf(float f){
  u32 u = __builtin_bit_cast(u32, f);
  u += 0x7fffu + ((u >> 16) & 1u);
  return (u16)(u >> 16);
}

#define GLDS16(gp, lp) __builtin_amdgcn_global_load_lds((const __attribute__((address_space(1))) void*)(gp), (__attribute__((address_space(3))) void*)(lp), 16, 0, 0)

__device__ __forceinline__ f32x4 mfma16(bf16x8 a, bf16x8 b, f32x4 c){
  return __builtin_amdgcn_mfma_f32_16x16x32_bf16(a, b, c, 0, 0, 0);
}
__device__ __forceinline__ f32x4 zero4(){ f32x4 v; v[0]=0.f; v[1]=0.f; v[2]=0.f; v[3]=0.f; return v; }

// ---------------- f32 -> bf16 converters ----------------
__global__ void cvt_kernel(const float* __restrict__ src, u16* __restrict__ dst, int n){
  int i = (blockIdx.x*256 + threadIdx.x)*4;
  if (i >= n) return;
  float4 v = *(const float4*)(src + i);
  u16 t[4] = {f2bf(v.x), f2bf(v.y), f2bf(v.z), f2bf(v.w)};
  *(uint2*)(dst + i) = *(const uint2*)t;
}

__global__ void procvt_kernel(const float* __restrict__ src, u16* __restrict__ dst){
  int i = (blockIdx.x*256 + threadIdx.x)*4;  // dst has 4992*256 elems, zero-pad tail
  u16 t[4];
  if (i < Bc*Hc){
    float4 v = *(const float4*)(src + i);
    t[0]=f2bf(v.x); t[1]=f2bf(v.y); t[2]=f2bf(v.z); t[3]=f2bf(v.w);
  } else { t[0]=t[1]=t[2]=t[3]=0; }
  *(uint2*)(dst + i) = *(const uint2*)t;
}

// dynw row-permuted cvt: row n of dyn_w goes to row pi(n) of dynwB so that the
// p1/p2 regions of params land directly in MFMA B-fragment order.
__device__ __forceinline__ int dynperm(int n){
  if (n < NPc){
    int h = n >> 6, d = n & 63;           // p1[h][d], K=h(256), N=d(64)
    return (d>>4)*4096 + (h>>5)*512 + ((h>>3)&3)*128 + (d&15)*8 + (h&7);
  } else {
    int m = n - NPc; int d = m >> 8, h = m & 255;   // p2[d][h], K=d(64), N=h(256)
    return NPc + (h>>4)*1024 + (d>>5)*512 + ((d>>3)&3)*128 + (h&15)*8 + (d&7);
  }
}

__global__ __launch_bounds__(256) void cvt_dynw_perm(const float* __restrict__ dynw,
    const float* __restrict__ dynb, u16* __restrict__ dynwB, float* __restrict__ dynbP){
  int idx = blockIdx.x*256 + threadIdx.x;   // 262144 total: 32768 rows x 8 parts
  int n = idx >> 3, p = idx & 7;
  int pn = dynperm(n);
  const float* s = dynw + (size_t)n*256 + p*32;
  u16 t[32];
  #pragma unroll
  for (int j = 0; j < 8; j++){
    float4 v = *(const float4*)(s + j*4);
    t[j*4+0]=f2bf(v.x); t[j*4+1]=f2bf(v.y); t[j*4+2]=f2bf(v.z); t[j*4+3]=f2bf(v.w);
  }
  u16* d = dynwB + (size_t)pn*256 + p*32;
  #pragma unroll
  for (int j = 0; j < 4; j++) ((uint4*)d)[j] = ((const uint4*)t)[j];
  if (p == 0) dynbP[pn] = dynb[n];
}

// ---------------- masks: sigmoid((pro@w1^T+b1)@w2^T+b2), 8 boxes/block ----------------
__global__ __launch_bounds__(256) void masks_kernel(const float* __restrict__ pro,
    const float* __restrict__ pc1w, const float* __restrict__ pc1b,
    const float* __restrict__ pc2w, const float* __restrict__ pc2b,
    const float* __restrict__ pr1w, const float* __restrict__ pr1b,
    const float* __restrict__ pr2w, const float* __restrict__ pr2b,
    float* __restrict__ mcls, float* __restrict__ mreg)
{
  __shared__ float rowv[8][256];
  __shared__ float hv[8][33];
  const int tid = threadIdx.x;
  const int bb = blockIdx.x*8;
  #pragma unroll
  for (int q = 0; q < 8; q++) rowv[q][tid] = pro[(size_t)(bb+q)*256 + tid];
  const int bx = tid >> 5, h = tid & 31;
  __syncthreads();
  for (int br = 0; br < 2; br++){
    const float* w1 = br ? pr1w : pc1w;
    const float* b1 = br ? pr1b : pc1b;
    const float* w2 = br ? pr2w : pc2w;
    const float* b2 = br ? pr2b : pc2b;
    float* outm = br ? mreg : mcls;
    {
      float s = b1[h];
      const float* wr = w1 + h*256;
      for (int k = 0; k < 256; k += 4){
        float4 wv = *(const float4*)(wr + k);
        s += rowv[bx][k]*wv.x + rowv[bx][k+1]*wv.y + rowv[bx][k+2]*wv.z + rowv[bx][k+3]*wv.w;
      }
      hv[bx][h] = s;
    }
    __syncthreads();
    int c0 = h*8;
    float o[8];
    #pragma unroll
    for (int j = 0; j < 8; j++){
      float s2 = b2[c0+j];
      const float* w2r = w2 + (c0+j)*32;
      #pragma unroll
      for (int j2 = 0; j2 < 32; j2 += 4){
        float4 wv = *(const float4*)(w2r + j2);
        s2 += hv[bx][j2]*wv.x + hv[bx][j2+1]*wv.y + hv[bx][j2+2]*wv.z + hv[bx][j2+3]*wv.w;
      }
      o[j] = 1.f/(1.f + expf(-s2));
    }
    float* dst = outm + (size_t)(bb+bx)*256 + c0;
    *(float4*)dst = make_float4(o[0],o[1],o[2],o[3]);
    *(float4*)(dst+4) = make_float4(o[4],o[5],o[6],o[7]);
    __syncthreads();
  }
}

// ---------------- GEMM1: params[C][32768] = proB @ dynwB^T + dynbP (bf16) ----------------
// BM=128 BN=128 BK=64, double-buffered, 512 threads, 64KB LDS -> 2 blocks/CU
__global__ __launch_bounds__(512, 4) void gemm1_kernel(const u16* __restrict__ proB,
    const u16* __restrict__ dynwB, const float* __restrict__ dynbP,
    u16* __restrict__ paramsOut, int b0, int C)
{
  __shared__ u16 sm[2][2][128*64];   // [buf][A=0/B=1][128 rows][64 k]
  const int tid = threadIdx.x;
  const int bx = blockIdx.x, by = blockIdx.y;
  const int l = tid & 63, wid = tid >> 6, l15 = l & 15, lg = l >> 4;
  const int wm = wid >> 2, wn = wid & 3;   // 2 x 4 waves, wave tile 64m x 32n
  const char* Abase = (const char*)proB;
  const char* Bbase = (const char*)dynwB;

  auto stage = [&](int t, int buf){
    #pragma unroll
    for (int p = 0; p < 2; p++){
      int base = (wid + p*8)*1024;
      int lin = base + l*16;
      int row = lin >> 7, cb = lin & 127;
      int swz = (row & 7) << 4;
      GLDS16(Abase + (size_t)(b0 + bx*128 + row)*512 + t*128 + (cb ^ swz),
             (char*)sm[buf][0] + base);
      GLDS16(Bbase + (size_t)(by*128 + row)*512 + t*128 + (cb ^ swz),
             (char*)sm[buf][1] + base);
    }
  };

  f32x4 acc[4][2];
  #pragma unroll
  for (int i=0;i<4;i++){ acc[i][0]=zero4(); acc[i][1]=zero4(); }

  stage(0, 0);
  __syncthreads();
  for (int t = 0; t < 4; t++){
    if (t < 3) stage(t+1, (t&1)^1);
    const char* sa = (const char*)sm[t&1][0];
    const char* sb = (const char*)sm[t&1][1];
    #pragma unroll
    for (int ks = 0; ks < 2; ks++){
      bf16x8 av[4], bv[2];
      #pragma unroll
      for (int mt=0; mt<4; mt++){
        int row = wm*64 + mt*16 + l15;
        av[mt] = *(const bf16x8*)(sa + row*128 + ((ks*64 + lg*16) ^ ((row&7)<<4)));
      }
      #pragma unroll
      for (int nt=0; nt<2; nt++){
        int row = wn*32 + nt*16 + l15;
        bv[nt] = *(const bf16x8*)(sb + row*128 + ((ks*64 + lg*16) ^ ((row&7)<<4)));
      }
      #pragma unroll
      for (int mt=0; mt<4; mt++)
        #pragma unroll
        for (int nt=0; nt<2; nt++)
          acc[mt][nt] = mfma16(av[mt], bv[nt], acc[mt][nt]);
    }
    __syncthreads();
  }
  // epilogue: + bias, ->bf16, stage in LDS, coalesced store
  float bb[2];
  #pragma unroll
  for (int nt=0; nt<2; nt++) bb[nt] = dynbP[by*128 + wn*32 + nt*16 + l15];
  char* tile = (char*)sm;   // 32KB
  #pragma unroll
  for (int mt=0; mt<4; mt++)
    #pragma unroll
    for (int nt=0; nt<2; nt++)
      #pragma unroll
      for (int r=0; r<4; r++){
        int row = wm*64 + mt*16 + lg*4 + r;
        int col = wn*32 + nt*16 + l15;
        *(u16*)(tile + row*256 + ((col*2) ^ ((row&7)<<4))) = f2bf(acc[mt][nt][r] + bb[nt]);
      }
  __syncthreads();
  #pragma unroll
  for (int p = 0; p < 4; p++){
    int lin = (tid + p*512)*16;
    int row = lin >> 8, cb = lin & 255;
    int rg = bx*128 + row;
    if (rg < C){
      uint4 v = *(const uint4*)(tile + row*256 + (cb ^ ((row&7)<<4)));
      *(uint4*)((char*)paramsOut + (size_t)rg*65536 + (size_t)by*256 + cb) = v;
    }
  }
}

// ---------------- fused conv: ALL operands direct global->VGPR, 1 barrier, 4 blocks/CU ----------------
// 4 waves; wave w owns rows 16w..16w+15. LDS: [0..32K) per-wave SY/out-tile, [32K..40K) SC.
__global__ __launch_bounds__(256, 4) void conv_kernel(const float* __restrict__ roi,
    const u16* __restrict__ params,
    const float* __restrict__ n1g, const float* __restrict__ n1b,
    const float* __restrict__ n2g, const float* __restrict__ n2b,
    const float* __restrict__ n3cg, const float* __restrict__ n3cb,
    const float* __restrict__ n3rg, const float* __restrict__ n3rb,
    const float* __restrict__ mcls, const float* __restrict__ mreg,
    u16* __restrict__ fcin, u16* __restrict__ frin, int b0)
{
  __shared__ char lds[40960];
  const int tid = threadIdx.x, bloc = blockIdx.x, b = b0 + bloc;
  const int l = tid & 63, w = tid >> 6, l15 = l & 15, lg = l >> 4;
  const char* pbase = (const char*)params + (size_t)bloc*65536;
  const int wbase = w*8192;
  const int arow = 16*w + l15;
  const int crow = (arow < Tc) ? arow : (Tc-1);       // clamp; garbage rows never contaminate valid rows
  const float* asrc = roi + ((size_t)crow*Bc + b)*256 + lg*8;

  // SC coef fill (cross-wave; covered by the single barrier below)
  float* SCf = (float*)(lds + 32768);
  {
    float mc = mcls[(size_t)b*256+tid], mr = mreg[(size_t)b*256+tid];
    float g2 = n2g[tid], b2v = n2b[tid];
    SCf[0*256+tid] = g2*mc; SCf[1*256+tid] = b2v*mc;
    SCf[2*256+tid] = n3cg[tid]; SCf[3*256+tid] = n3cb[tid];
    SCf[4*256+tid] = g2*mr; SCf[5*256+tid] = b2v*mr;
    SCf[6*256+tid] = n3rg[tid]; SCf[7*256+tid] = n3rb[tid];
  }

  // ---- phase 1: x = feats @ p1, kk = 0..7, fragments loaded direct, 1-deep pipeline ----
  const char* p1a = pbase + lg*256 + l15*16;
  f32x4 xacc[4];
  #pragma unroll
  for (int i=0;i<4;i++) xacc[i] = zero4();

  f32x4 aA0, aA1, aB0, aB1;
  bf16x8 bA[4], bB[4];
  aA0 = *(const f32x4*)(asrc);  aA1 = *(const f32x4*)(asrc + 4);
  #pragma unroll
  for (int nt=0; nt<4; nt++) bA[nt] = *(const bf16x8*)(p1a + nt*8192);
  #pragma unroll
  for (int kk = 0; kk < 8; kk++){
    if (kk & 1){
      if (kk < 7){
        aA0 = *(const f32x4*)(asrc + (kk+1)*32); aA1 = *(const f32x4*)(asrc + (kk+1)*32 + 4);
        #pragma unroll
        for (int nt=0; nt<4; nt++) bA[nt] = *(const bf16x8*)(p1a + nt*8192 + (kk+1)*1024);
      }
      bf16x8 af;
      #pragma unroll
      for (int j=0;j<4;j++){ af[j] = (__bf16)aB0[j]; af[4+j] = (__bf16)aB1[j]; }
      #pragma unroll
      for (int nt=0; nt<4; nt++) xacc[nt] = mfma16(af, bB[nt], xacc[nt]);
    } else {
      aB0 = *(const f32x4*)(asrc + (kk+1)*32); aB1 = *(const f32x4*)(asrc + (kk+1)*32 + 4);
      #pragma unroll
      for (int nt=0; nt<4; nt++) bB[nt] = *(const bf16x8*)(p1a + nt*8192 + (kk+1)*1024);
      bf16x8 af;
      #pragma unroll
      for (int j=0;j<4;j++){ af[j] = (__bf16)aA0[j]; af[4+j] = (__bf16)aA1[j]; }
      #pragma unroll
      for (int nt=0; nt<4; nt++) xacc[nt] = mfma16(af, bA[nt], xacc[nt]);
    }
  }

  // ---- LN1 + write y to wave-local SY (no barrier: same-wave DS ordering) ----
  {
    float g1v[4], b1v[4];
    #pragma unroll
    for (int nt=0; nt<4; nt++){ g1v[nt] = n1g[nt*16+l15]; b1v[nt] = n1b[nt*16+l15]; }
    #pragma unroll
    for (int r = 0; r < 4; r++){
      float s = xacc[0][r]+xacc[1][r]+xacc[2][r]+xacc[3][r];
      float q = xacc[0][r]*xacc[0][r]+xacc[1][r]*xacc[1][r]
              + xacc[2][r]*xacc[2][r]+xacc[3][r]*xacc[3][r];
      #pragma unroll
      for (int m = 1; m < 16; m <<= 1){ s += __shfl_xor(s, m); q += __shfl_xor(q, m); }
      float mu = s*(1.f/64.f);
      float rs = rsqrtf(q*(1.f/64.f) - mu*mu + 1e-5f);
      int lr = lg*4 + r;
      int swz = (lr & 7) << 4;
      #pragma unroll
      for (int nt=0; nt<4; nt++){
        float yv = fmaxf((xacc[nt][r]-mu)*rs*g1v[nt] + b1v[nt], 0.f);
        *(u16*)(lds + wbase + lr*128 + ((2*(nt*16+l15)) ^ swz)) = f2bf(yv);
      }
    }
  }

  // ---- phase 2: x2 = y @ p2; A from wave-local SY, B direct global, pipelined ----
  bf16x8 ay[2];
  #pragma unroll
  for (int ks=0; ks<2; ks++)
    ay[ks] = *(const bf16x8*)(lds + wbase + l15*128 + ((ks*64 + lg*16) ^ ((l15&7)<<4)));

  const char* p2a = pbase + 32768 + lg*256 + l15*16;
  f32x4 acc[16];
  #pragma unroll
  for (int i=0;i<16;i++) acc[i] = zero4();
  bf16x8 pA[4], pB[4];
  #pragma unroll
  for (int nt2=0; nt2<4; nt2++) pA[nt2] = *(const bf16x8*)(p2a + nt2*2048);
  #pragma unroll
  for (int idx = 0; idx < 8; idx++){
    int ks = idx >> 2, g = idx & 3;
    if (idx & 1){
      if (idx < 7){
        int ks2 = (idx+1)>>2, g2 = (idx+1)&3;
        #pragma unroll
        for (int nt2=0; nt2<4; nt2++) pA[nt2] = *(const bf16x8*)(p2a + (g2*4+nt2)*2048 + ks2*1024);
      }
      #pragma unroll
      for (int nt2=0; nt2<4; nt2++) acc[g*4+nt2] = mfma16(ay[ks], pB[nt2], acc[g*4+nt2]);
    } else {
      int ks2 = (idx+1)>>2, g2 = (idx+1)&3;
      #pragma unroll
      for (int nt2=0; nt2<4; nt2++) pB[nt2] = *(const bf16x8*)(p2a + (g2*4+nt2)*2048 + ks2*1024);
      #pragma unroll
      for (int nt2=0; nt2<4; nt2++) acc[g*4+nt2] = mfma16(ay[ks], pA[nt2], acc[g*4+nt2]);
    }
  }

  // ---- LN2: stats over 256 cols, keep xhat in accumulators ----
  #pragma unroll
  for (int r = 0; r < 4; r++){
    float s = 0.f, q = 0.f;
    #pragma unroll
    for (int nt=0; nt<16; nt++){ float v = acc[nt][r]; s += v; q += v*v; }
    #pragma unroll
    for (int m = 1; m < 16; m <<= 1){ s += __shfl_xor(s, m); q += __shfl_xor(q, m); }
    float mu = s*(1.f/256.f);
    float rs = rsqrtf(q*(1.f/256.f) - mu*mu + 1e-5f);
    #pragma unroll
    for (int nt=0; nt<16; nt++) acc[nt][r] = (acc[nt][r]-mu)*rs;
  }

  __syncthreads();   // the ONLY barrier: SC coefs visible to all waves

  // ---- branches: u = relu(xhat*gm + bm); LN3; relu; wave-local tile + copy ----
  for (int br = 0; br < 2; br++){
    float s3[4] = {0.f,0.f,0.f,0.f}, q3[4] = {0.f,0.f,0.f,0.f};
    #pragma unroll
    for (int nt=0; nt<16; nt++){
      int col = nt*16 + l15;
      float gm = SCf[(4*br)*256 + col], bm = SCf[(4*br+1)*256 + col];
      #pragma unroll
      for (int r=0; r<4; r++){
        float u = fmaxf(acc[nt][r]*gm + bm, 0.f);
        s3[r] += u; q3[r] += u*u;
      }
    }
    float m3[4], r3[4];
    #pragma unroll
    for (int r=0; r<4; r++){
      float s = s3[r], q = q3[r];
      #pragma unroll
      for (int m = 1; m < 16; m <<= 1){ s += __shfl_xor(s, m); q += __shfl_xor(q, m); }
      float mu = s*(1.f/256.f);
      m3[r] = mu; r3[r] = rsqrtf(q*(1.f/256.f) - mu*mu + 1e-5f);
    }
    #pragma unroll
    for (int nt=0; nt<16; nt++){
      int col = nt*16 + l15;
      float gm = SCf[(4*br)*256 + col], bm = SCf[(4*br+1)*256 + col];
      float g3 = SCf[(4*br+2)*256 + col], b3 = SCf[(4*br+3)*256 + col];
      #pragma unroll
      for (int r=0; r<4; r++){
        int row = 16*w + lg*4 + r;
        float u = fmaxf(acc[nt][r]*gm + bm, 0.f);
        float f = fmaxf((u - m3[r])*r3[r]*g3 + b3, 0.f);
        *(u16*)(lds + row*512 + ((2*col) ^ ((row&7)<<4))) = f2bf(f);
      }
    }
    // wave-local copy out (rows 16w..16w+15); same-wave DS ordering, no barrier
    {
      u16* outp = (br ? frin : fcin) + (size_t)b * KOUT;
      #pragma unroll
      for (int p = 0; p < 8; p++){
        int off = w*8192 + p*1024 + l*16;
        int row = off >> 9;
        if (row < Tc){
          int cb = off & 511;
          uint4 v = *(const uint4*)(lds + row*512 + (cb ^ ((row&7)<<4)));
          *(uint4*)((char*)outp + off) = v;
        }
      }
    }
  }
}

// ---------------- outGEMM partial (LDS-staged): pbuf[(z*8+sp)][4800][256] ----------------
__global__ __launch_bounds__(256, 4) void outgemm_part(
    const u16* __restrict__ fcin, const u16* __restrict__ frin,
    const u16* __restrict__ ocw, const u16* __restrict__ orw,
    float* __restrict__ pbuf)
{
  __shared__ u16 smA[64*64];
  __shared__ u16 smB[256*64];
  const int tid = threadIdx.x;
  const int z = blockIdx.y, sp = blockIdx.z;
  const int m0 = blockIdx.x * 64;
  const u16* A = z ? frin : fcin;
  const u16* W = z ? orw : ocw;
  const int l = tid & 63, w = tid >> 6, l15 = l & 15, lg = l >> 4;

  f32x4 acc[4][4];
  #pragma unroll
  for (int i=0;i<4;i++)
    #pragma unroll
    for (int j=0;j<4;j++) acc[i][j] = zero4();

  // 196 kt-tiles split 8 ways: [ (sp*49)>>1 , ((sp+1)*49)>>1 )
  const int kt0 = (sp*49) >> 1, kt1 = ((sp+1)*49) >> 1;
  for (int kt = kt0; kt < kt1; kt++){
    #pragma unroll
    for (int p = 0; p < 2; p++){
      int base = (w + p*4)*1024;
      int lin = base + l*16;
      int row = lin >> 7, cb = lin & 127;
      GLDS16((const char*)A + (size_t)(m0 + row)*25088 + kt*128 + (cb ^ ((row & 7) << 4)), (char*)smA + base);
    }
    #pragma unroll
    for (int p = 0; p < 8; p++){
      int base = (w + p*4)*1024;
      int lin = base + l*16;
      int n = lin >> 7, cb = lin & 127;
      GLDS16((const char*)W + (size_t)n*25088 + kt*128 + (cb ^ ((n & 7) << 4)), (char*)smB + base);
    }
    __syncthreads();
    #pragma unroll
    for (int ks = 0; ks < 2; ks++){
      bf16x8 av[4], bv[4];
      #pragma unroll
      for (int mt=0; mt<4; mt++){
        int row = mt*16 + l15;
        av[mt] = *(const bf16x8*)((const char*)smA + row*128 + ((ks*64 + lg*16) ^ ((row&7)<<4)));
      }
      #pragma unroll
      for (int nt=0; nt<4; nt++){
        int row = w*64 + nt*16 + l15;
        bv[nt] = *(const bf16x8*)((const char*)smB + row*128 + ((ks*64 + lg*16) ^ ((row&7)<<4)));
      }
      #pragma unroll
      for (int mt=0; mt<4; mt++)
        #pragma unroll
        for (int nt=0; nt<4; nt++)
          acc[mt][nt] = mfma16(av[mt], bv[nt], acc[mt][nt]);
    }
    __syncthreads();
  }
  float* pb = pbuf + ((size_t)(z*8 + sp)*Bc)*256;
  #pragma unroll
  for (int mt=0; mt<4; mt++)
    #pragma unroll
    for (int r=0; r<4; r++){
      int row = m0 + mt*16 + lg*4 + r;
      #pragma unroll
      for (int nt=0; nt<4; nt++)
        pb[(size_t)row*256 + w*64 + nt*16 + l15] = acc[mt][nt][r];
    }
}

// ---------------- LN4 finisher: sum 8 partials + bias, LN, relu -> fp32 out ----------------
__global__ __launch_bounds__(256) void ln4fin(const float* __restrict__ pbuf,
    const float* __restrict__ ocb, const float* __restrict__ orb,
    const float* __restrict__ n4cg, const float* __restrict__ n4cb,
    const float* __restrict__ n4rg, const float* __restrict__ n4rb,
    float* __restrict__ dout)
{
  int R = blockIdx.x*4 + (threadIdx.x >> 6);
  int z = R >= Bc;
  int box = R - z*Bc;
  int lane = threadIdx.x & 63;
  int col = lane*4;
  float4 v = make_float4(0.f,0.f,0.f,0.f);
  #pragma unroll
  for (int s = 0; s < 8; s++){
    float4 p = *(const float4*)(pbuf + ((size_t)(z*8 + s)*Bc + box)*256 + col);
    v.x += p.x; v.y += p.y; v.z += p.z; v.w += p.w;
  }
  float4 bi = *(const float4*)((z ? orb : ocb) + col);
  v.x += bi.x; v.y += bi.y; v.z += bi.z; v.w += bi.w;
  float s = v.x+v.y+v.z+v.w;
  float q = v.x*v.x+v.y*v.y+v.z*v.z+v.w*v.w;
  #pragma unroll
  for (int m = 1; m < 64; m <<= 1){ s += __shfl_xor(s, m); q += __shfl_xor(q, m); }
  float mu = s*(1.f/256.f);
  float rs = rsqrtf(q*(1.f/256.f) - mu*mu + 1e-5f);
  float4 g = *(const float4*)((z ? n4rg : n4cg) + col);
  float4 bb = *(const float4*)((z ? n4rb : n4cb) + col);
  float4 o;
  o.x = fmaxf((v.x-mu)*rs*g.x + bb.x, 0.f);
  o.y = fmaxf((v.y-mu)*rs*g.y + bb.y, 0.f);
  o.z = fmaxf((v.z-mu)*rs*g.z + bb.z, 0.f);
  o.w = fmaxf((v.w-mu)*rs*g.w + bb.w, 0.f);
  *(float4*)(dout + (size_t)z*OUTSTRIDE + (size_t)box*256 + col) = o;
}

extern "C" void kernel_launch(void* const* d_in, const int* in_sizes, int n_in,
                              void* d_out, int out_size, void* d_ws, size_t ws_size,
                              hipStream_t stream)
{
  (void)in_sizes; (void)n_in; (void)out_size;
  const float* pro  = (const float*)d_in[0];
  const float* roi  = (const float*)d_in[1];
  const float* dynw = (const float*)d_in[2];
  const float* dynb = (const float*)d_in[3];
  const float* n1g = (const float*)d_in[4];
  const float* n1b = (const float*)d_in[5];
  const float* n2g = (const float*)d_in[6];
  const float* n2b = (const float*)d_in[7];
  const float* pc1w = (const float*)d_in[8];
  const float* pc1b = (const float*)d_in[9];
  const float* pc2w = (const float*)d_in[10];
  const float* pc2b = (const float*)d_in[11];
  const float* n3cg = (const float*)d_in[12];
  const float* n3cb = (const float*)d_in[13];
  const float* pr1w = (const float*)d_in[14];
  const float* pr1b = (const float*)d_in[15];
  const float* pr2w = (const float*)d_in[16];
  const float* pr2b = (const float*)d_in[17];
  const float* n3rg = (const float*)d_in[18];
  const float* n3rb = (const float*)d_in[19];
  const float* ocw = (const float*)d_in[20];
  const float* ocb = (const float*)d_in[21];
  const float* n4cg = (const float*)d_in[22];
  const float* n4cb = (const float*)d_in[23];
  const float* orw = (const float*)d_in[24];
  const float* orb = (const float*)d_in[25];
  const float* n4rg = (const float*)d_in[26];
  const float* n4rb = (const float*)d_in[27];
  float* dout = (float*)d_out;

  char* ws = (char*)d_ws;
  size_t off = 0;
  auto alloc = [&](size_t bytes) -> char* {
    char* p = ws + off;
    off += (bytes + 255) & ~(size_t)255;
    return p;
  };
  u16* dynwB = (u16*)alloc((size_t)32768*256*2);
  float* dynbP = (float*)alloc((size_t)32768*4);
  u16* ocwB  = (u16*)alloc((size_t)12544*256*2);
  u16* orwB  = (u16*)alloc((size_t)12544*256*2);
  u16* proB  = (u16*)alloc((size_t)4992*256*2);
  float* mcls = (float*)alloc((size_t)4800*256*4);
  float* mreg = (float*)alloc((size_t)4800*256*4);
  u16* fcinF  = (u16*)alloc((size_t)Bc*25088);          // full 4800 boxes
  u16* frinF  = (u16*)alloc((size_t)Bc*25088);
  float* pbufF = (float*)alloc((size_t)16*Bc*256*4);    // 16 partials x 4800 x 256
  size_t fixedOff = off;

  // params chunk: keep L3-resident between gemm1 and conv
  int C = 480;
  const int copts[] = {1200, 960, 800, 600, 480};
  for (int i = 0; i < (int)(sizeof(copts)/sizeof(int)); i++){
    size_t need = fixedOff + (size_t)copts[i]*65536;
    if (need <= ws_size){ C = copts[i]; break; }
  }
  u16* paramsC = (u16*)alloc((size_t)C*65536);

  cvt_dynw_perm<<<1024, 256, 0, stream>>>(dynw, dynb, dynwB, dynbP);
  cvt_kernel<<<3136, 256, 0, stream>>>(ocw, ocwB, 12544*256);
  cvt_kernel<<<3136, 256, 0, stream>>>(orw, orwB, 12544*256);
  procvt_kernel<<<1248, 256, 0, stream>>>(pro, proB);
  masks_kernel<<<600, 256, 0, stream>>>(pro, pc1w, pc1b, pc2w, pc2b,
                                        pr1w, pr1b, pr2w, pr2b, mcls, mreg);
  int nch = (Bc + C - 1) / C;
  for (int c = 0; c < nch; c++){
    int b0 = c*C;
    int Cc = (b0 + C <= Bc) ? C : (Bc - b0);
    gemm1_kernel<<<dim3((Cc+127)/128, 256), 512, 0, stream>>>(proB, dynwB, dynbP, paramsC, b0, Cc);
    conv_kernel<<<Cc, 256, 0, stream>>>(roi, paramsC, n1g, n1b, n2g, n2b,
                                        n3cg, n3cb, n3rg, n3rb, mcls, mreg,
                                        fcinF, frinF, b0);
  }
  outgemm_part<<<dim3(75, 2, 8), 256, 0, stream>>>(fcinF, frinF, ocwB, orwB, pbufF);
  ln4fin<<<2400, 256, 0, stream>>>(pbufF, ocb, orb, n4cg, n4cb, n4rg, n4rb, dout);
}

// Round 9
// 834.275 us; speedup vs baseline: 1.3243x; 1.3243x over previous
//
#include <hip/hip_runtime.h>

#define Hc 256
#define Dc 64
#define Tc 49
#define Bc 4800
#define NPc 16384
#define KOUT 12544          // T*H
#define OUTSTRIDE 1228800   // 4800*256

typedef unsigned short u16;
typedef unsigned int u32;
typedef __bf16 bf16x8 __attribute__((ext_vector_type(8)));
typedef float f32x4 __attribute__((ext_vector_type(4)));

__device__ __forceinline__ u16 f2bf(float f){
  u32 u = __builtin_bit_cast(u32, f);
  u += 0x7fffu + ((u >> 16) & 1u);
  return (u16)(u >> 16);
}

#define GLDS16(gp, lp) __builtin_amdgcn_global_load_lds((const __attribute__((address_space(1))) void*)(gp), (__attribute__((address_space(3))) void*)(lp), 16, 0, 0)

__device__ __forceinline__ f32x4 mfma16(bf16x8 a, bf16x8 b, f32x4 c){
  return __builtin_amdgcn_mfma_f32_16x16x32_bf16(a, b, c, 0, 0, 0);
}
__device__ __forceinline__ f32x4 zero4(){ f32x4 v; v[0]=0.f; v[1]=0.f; v[2]=0.f; v[3]=0.f; return v; }

// ---------------- f32 -> bf16 converters ----------------
__global__ void cvt_kernel(const float* __restrict__ src, u16* __restrict__ dst, int n){
  int i = (blockIdx.x*256 + threadIdx.x)*4;
  if (i >= n) return;
  float4 v = *(const float4*)(src + i);
  u16 t[4] = {f2bf(v.x), f2bf(v.y), f2bf(v.z), f2bf(v.w)};
  *(uint2*)(dst + i) = *(const uint2*)t;
}

__global__ void procvt_kernel(const float* __restrict__ src, u16* __restrict__ dst){
  int i = (blockIdx.x*256 + threadIdx.x)*4;  // dst has 4992*256 elems, zero-pad tail
  u16 t[4];
  if (i < Bc*Hc){
    float4 v = *(const float4*)(src + i);
    t[0]=f2bf(v.x); t[1]=f2bf(v.y); t[2]=f2bf(v.z); t[3]=f2bf(v.w);
  } else { t[0]=t[1]=t[2]=t[3]=0; }
  *(uint2*)(dst + i) = *(const uint2*)t;
}

// dynw row-permuted cvt: row n of dyn_w goes to row pi(n) of dynwB so that the
// p1/p2 regions of params land directly in MFMA B-fragment order.
__device__ __forceinline__ int dynperm(int n){
  if (n < NPc){
    int h = n >> 6, d = n & 63;           // p1[h][d], K=h(256), N=d(64)
    return (d>>4)*4096 + (h>>5)*512 + ((h>>3)&3)*128 + (d&15)*8 + (h&7);
  } else {
    int m = n - NPc; int d = m >> 8, h = m & 255;   // p2[d][h], K=d(64), N=h(256)
    return NPc + (h>>4)*1024 + (d>>5)*512 + ((d>>3)&3)*128 + (h&15)*8 + (d&7);
  }
}

__global__ __launch_bounds__(256) void cvt_dynw_perm(const float* __restrict__ dynw,
    const float* __restrict__ dynb, u16* __restrict__ dynwB, float* __restrict__ dynbP){
  int idx = blockIdx.x*256 + threadIdx.x;   // 262144 total: 32768 rows x 8 parts
  int n = idx >> 3, p = idx & 7;
  int pn = dynperm(n);
  const float* s = dynw + (size_t)n*256 + p*32;
  u16 t[32];
  #pragma unroll
  for (int j = 0; j < 8; j++){
    float4 v = *(const float4*)(s + j*4);
    t[j*4+0]=f2bf(v.x); t[j*4+1]=f2bf(v.y); t[j*4+2]=f2bf(v.z); t[j*4+3]=f2bf(v.w);
  }
  u16* d = dynwB + (size_t)pn*256 + p*32;
  #pragma unroll
  for (int j = 0; j < 4; j++) ((uint4*)d)[j] = ((const uint4*)t)[j];
  if (p == 0) dynbP[pn] = dynb[n];
}

// ---------------- masks: sigmoid((pro@w1^T+b1)@w2^T+b2), 8 boxes/block ----------------
__global__ __launch_bounds__(256) void masks_kernel(const float* __restrict__ pro,
    const float* __restrict__ pc1w, const float* __restrict__ pc1b,
    const float* __restrict__ pc2w, const float* __restrict__ pc2b,
    const float* __restrict__ pr1w, const float* __restrict__ pr1b,
    const float* __restrict__ pr2w, const float* __restrict__ pr2b,
    float* __restrict__ mcls, float* __restrict__ mreg)
{
  __shared__ float rowv[8][256];
  __shared__ float hv[8][33];
  const int tid = threadIdx.x;
  const int bb = blockIdx.x*8;
  #pragma unroll
  for (int q = 0; q < 8; q++) rowv[q][tid] = pro[(size_t)(bb+q)*256 + tid];
  const int bx = tid >> 5, h = tid & 31;
  __syncthreads();
  for (int br = 0; br < 2; br++){
    const float* w1 = br ? pr1w : pc1w;
    const float* b1 = br ? pr1b : pc1b;
    const float* w2 = br ? pr2w : pc2w;
    const float* b2 = br ? pr2b : pc2b;
    float* outm = br ? mreg : mcls;
    {
      float s = b1[h];
      const float* wr = w1 + h*256;
      for (int k = 0; k < 256; k += 4){
        float4 wv = *(const float4*)(wr + k);
        s += rowv[bx][k]*wv.x + rowv[bx][k+1]*wv.y + rowv[bx][k+2]*wv.z + rowv[bx][k+3]*wv.w;
      }
      hv[bx][h] = s;
    }
    __syncthreads();
    int c0 = h*8;
    float o[8];
    #pragma unroll
    for (int j = 0; j < 8; j++){
      float s2 = b2[c0+j];
      const float* w2r = w2 + (c0+j)*32;
      #pragma unroll
      for (int j2 = 0; j2 < 32; j2 += 4){
        float4 wv = *(const float4*)(w2r + j2);
        s2 += hv[bx][j2]*wv.x + hv[bx][j2+1]*wv.y + hv[bx][j2+2]*wv.z + hv[bx][j2+3]*wv.w;
      }
      o[j] = 1.f/(1.f + expf(-s2));
    }
    float* dst = outm + (size_t)(bb+bx)*256 + c0;
    *(float4*)dst = make_float4(o[0],o[1],o[2],o[3]);
    *(float4*)(dst+4) = make_float4(o[4],o[5],o[6],o[7]);
    __syncthreads();
  }
}

// ---------------- GEMM1: params[C][32768] = proB @ dynwB^T + dynbP (bf16) ----------------
// BM=128 BN=128 BK=64, double-buffered, 512 threads, 64KB LDS -> 2 blocks/CU
__global__ __launch_bounds__(512, 4) void gemm1_kernel(const u16* __restrict__ proB,
    const u16* __restrict__ dynwB, const float* __restrict__ dynbP,
    u16* __restrict__ paramsOut, int b0, int C)
{
  __shared__ u16 sm[2][2][128*64];   // [buf][A=0/B=1][128 rows][64 k]
  const int tid = threadIdx.x;
  const int bx = blockIdx.x, by = blockIdx.y;
  const int l = tid & 63, wid = tid >> 6, l15 = l & 15, lg = l >> 4;
  const int wm = wid >> 2, wn = wid & 3;   // 2 x 4 waves, wave tile 64m x 32n
  const char* Abase = (const char*)proB;
  const char* Bbase = (const char*)dynwB;

  auto stage = [&](int t, int buf){
    #pragma unroll
    for (int p = 0; p < 2; p++){
      int base = (wid + p*8)*1024;
      int lin = base + l*16;
      int row = lin >> 7, cb = lin & 127;
      int swz = (row & 7) << 4;
      GLDS16(Abase + (size_t)(b0 + bx*128 + row)*512 + t*128 + (cb ^ swz),
             (char*)sm[buf][0] + base);
      GLDS16(Bbase + (size_t)(by*128 + row)*512 + t*128 + (cb ^ swz),
             (char*)sm[buf][1] + base);
    }
  };

  f32x4 acc[4][2];
  #pragma unroll
  for (int i=0;i<4;i++){ acc[i][0]=zero4(); acc[i][1]=zero4(); }

  stage(0, 0);
  __syncthreads();
  for (int t = 0; t < 4; t++){
    if (t < 3) stage(t+1, (t&1)^1);
    const char* sa = (const char*)sm[t&1][0];
    const char* sb = (const char*)sm[t&1][1];
    #pragma unroll
    for (int ks = 0; ks < 2; ks++){
      bf16x8 av[4], bv[2];
      #pragma unroll
      for (int mt=0; mt<4; mt++){
        int row = wm*64 + mt*16 + l15;
        av[mt] = *(const bf16x8*)(sa + row*128 + ((ks*64 + lg*16) ^ ((row&7)<<4)));
      }
      #pragma unroll
      for (int nt=0; nt<2; nt++){
        int row = wn*32 + nt*16 + l15;
        bv[nt] = *(const bf16x8*)(sb + row*128 + ((ks*64 + lg*16) ^ ((row&7)<<4)));
      }
      #pragma unroll
      for (int mt=0; mt<4; mt++)
        #pragma unroll
        for (int nt=0; nt<2; nt++)
          acc[mt][nt] = mfma16(av[mt], bv[nt], acc[mt][nt]);
    }
    __syncthreads();
  }
  // epilogue: + bias, ->bf16, stage in LDS, coalesced store
  float bb[2];
  #pragma unroll
  for (int nt=0; nt<2; nt++) bb[nt] = dynbP[by*128 + wn*32 + nt*16 + l15];
  char* tile = (char*)sm;   // 32KB
  #pragma unroll
  for (int mt=0; mt<4; mt++)
    #pragma unroll
    for (int nt=0; nt<2; nt++)
      #pragma unroll
      for (int r=0; r<4; r++){
        int row = wm*64 + mt*16 + lg*4 + r;
        int col = wn*32 + nt*16 + l15;
        *(u16*)(tile + row*256 + ((col*2) ^ ((row&7)<<4))) = f2bf(acc[mt][nt][r] + bb[nt]);
      }
  __syncthreads();
  #pragma unroll
  for (int p = 0; p < 4; p++){
    int lin = (tid + p*512)*16;
    int row = lin >> 8, cb = lin & 255;
    int rg = bx*128 + row;
    if (rg < C){
      uint4 v = *(const uint4*)(tile + row*256 + (cb ^ ((row&7)<<4)));
      *(uint4*)((char*)paramsOut + (size_t)rg*65536 + (size_t)by*256 + cb) = v;
    }
  }
}

// ---------------- fused conv v3: p2 GLDS-prefetched at entry; phase-1 direct; 2 barriers ----------------
// 4 waves; wave w owns rows 16w..16w+15.
// LDS: [0..32K) p2 frag-order (later out-tile), [32K..40K) per-wave SY, [40K..48K) SC.
__global__ __launch_bounds__(256, 3) void conv_kernel(const float* __restrict__ roi,
    const u16* __restrict__ params,
    const float* __restrict__ n1g, const float* __restrict__ n1b,
    const float* __restrict__ n2g, const float* __restrict__ n2b,
    const float* __restrict__ n3cg, const float* __restrict__ n3cb,
    const float* __restrict__ n3rg, const float* __restrict__ n3rb,
    const float* __restrict__ mcls, const float* __restrict__ mreg,
    u16* __restrict__ fcin, u16* __restrict__ frin, int b0)
{
  __shared__ char lds[49152];
  const int tid = threadIdx.x, bloc = blockIdx.x, b = b0 + bloc;
  const int l = tid & 63, w = tid >> 6, l15 = l & 15, lg = l >> 4;
  const char* pbase = (const char*)params + (size_t)bloc*65536;
  const int arow = 16*w + l15;
  const int crow = (arow < Tc) ? arow : (Tc-1);       // clamp; garbage rows never contaminate valid rows
  const float* asrc = roi + ((size_t)crow*Bc + b)*256 + lg*8;

  // issue p2 staging FIRST -- lands in LDS during phase-1 compute
  #pragma unroll
  for (int p = 0; p < 8; p++)
    GLDS16(pbase + 32768 + p*4096 + w*1024 + l*16, lds + p*4096 + w*1024);

  // SC coef fill (cross-wave; visible after barrier #1)
  float* SCf = (float*)(lds + 40960);
  {
    float mc = mcls[(size_t)b*256+tid], mr = mreg[(size_t)b*256+tid];
    float g2 = n2g[tid], b2v = n2b[tid];
    SCf[0*256+tid] = g2*mc; SCf[1*256+tid] = b2v*mc;
    SCf[2*256+tid] = n3cg[tid]; SCf[3*256+tid] = n3cb[tid];
    SCf[4*256+tid] = g2*mr; SCf[5*256+tid] = b2v*mr;
    SCf[6*256+tid] = n3rg[tid]; SCf[7*256+tid] = n3rb[tid];
  }

  // ---- phase 1: x = feats @ p1, direct global->VGPR, 1-deep pipeline ----
  const char* p1a = pbase + lg*256 + l15*16;
  f32x4 xacc[4];
  #pragma unroll
  for (int i=0;i<4;i++) xacc[i] = zero4();

  f32x4 aA0, aA1, aB0, aB1;
  bf16x8 bA[4], bB[4];
  aA0 = *(const f32x4*)(asrc);  aA1 = *(const f32x4*)(asrc + 4);
  #pragma unroll
  for (int nt=0; nt<4; nt++) bA[nt] = *(const bf16x8*)(p1a + nt*8192);
  #pragma unroll
  for (int kk = 0; kk < 8; kk++){
    if (kk & 1){
      if (kk < 7){
        aA0 = *(const f32x4*)(asrc + (kk+1)*32); aA1 = *(const f32x4*)(asrc + (kk+1)*32 + 4);
        #pragma unroll
        for (int nt=0; nt<4; nt++) bA[nt] = *(const bf16x8*)(p1a + nt*8192 + (kk+1)*1024);
      }
      bf16x8 af;
      #pragma unroll
      for (int j=0;j<4;j++){ af[j] = (__bf16)aB0[j]; af[4+j] = (__bf16)aB1[j]; }
      #pragma unroll
      for (int nt=0; nt<4; nt++) xacc[nt] = mfma16(af, bB[nt], xacc[nt]);
    } else {
      aB0 = *(const f32x4*)(asrc + (kk+1)*32); aB1 = *(const f32x4*)(asrc + (kk+1)*32 + 4);
      #pragma unroll
      for (int nt=0; nt<4; nt++) bB[nt] = *(const bf16x8*)(p1a + nt*8192 + (kk+1)*1024);
      bf16x8 af;
      #pragma unroll
      for (int j=0;j<4;j++){ af[j] = (__bf16)aA0[j]; af[4+j] = (__bf16)aA1[j]; }
      #pragma unroll
      for (int nt=0; nt<4; nt++) xacc[nt] = mfma16(af, bA[nt], xacc[nt]);
    }
  }

  // ---- LN1 + write y to per-wave SY at [32K + w*2K) (same-wave DS ordering) ----
  {
    float g1v[4], b1v[4];
    #pragma unroll
    for (int nt=0; nt<4; nt++){ g1v[nt] = n1g[nt*16+l15]; b1v[nt] = n1b[nt*16+l15]; }
    #pragma unroll
    for (int r = 0; r < 4; r++){
      float s = xacc[0][r]+xacc[1][r]+xacc[2][r]+xacc[3][r];
      float q = xacc[0][r]*xacc[0][r]+xacc[1][r]*xacc[1][r]
              + xacc[2][r]*xacc[2][r]+xacc[3][r]*xacc[3][r];
      #pragma unroll
      for (int m = 1; m < 16; m <<= 1){ s += __shfl_xor(s, m); q += __shfl_xor(q, m); }
      float mu = s*(1.f/64.f);
      float rs = rsqrtf(q*(1.f/64.f) - mu*mu + 1e-5f);
      int lr = lg*4 + r;
      int swz = (lr & 7) << 4;
      #pragma unroll
      for (int nt=0; nt<4; nt++){
        float yv = fmaxf((xacc[nt][r]-mu)*rs*g1v[nt] + b1v[nt], 0.f);
        *(u16*)(lds + 32768 + w*2048 + lr*128 + ((2*(nt*16+l15)) ^ swz)) = f2bf(yv);
      }
    }
  }

  __syncthreads();   // barrier #1: p2 staged (vmcnt drained) + SC visible

  // ---- phase 2: x2 = y @ p2; A from SY, B from LDS p2 (no global stalls) ----
  bf16x8 ay[2];
  #pragma unroll
  for (int ks=0; ks<2; ks++)
    ay[ks] = *(const bf16x8*)(lds + 32768 + w*2048 + l15*128 + ((ks*64 + lg*16) ^ ((l15&7)<<4)));

  f32x4 acc[16];
  #pragma unroll
  for (int i=0;i<16;i++) acc[i] = zero4();
  #pragma unroll
  for (int nt = 0; nt < 16; nt++){
    #pragma unroll
    for (int ks = 0; ks < 2; ks++){
      bf16x8 bp = *(const bf16x8*)(lds + nt*2048 + ks*1024 + lg*256 + l15*16);
      acc[nt] = mfma16(ay[ks], bp, acc[nt]);
    }
  }

  // ---- LN2: stats over 256 cols, keep xhat in accumulators ----
  #pragma unroll
  for (int r = 0; r < 4; r++){
    float s = 0.f, q = 0.f;
    #pragma unroll
    for (int nt=0; nt<16; nt++){ float v = acc[nt][r]; s += v; q += v*v; }
    #pragma unroll
    for (int m = 1; m < 16; m <<= 1){ s += __shfl_xor(s, m); q += __shfl_xor(q, m); }
    float mu = s*(1.f/256.f);
    float rs = rsqrtf(q*(1.f/256.f) - mu*mu + 1e-5f);
    #pragma unroll
    for (int nt=0; nt<16; nt++) acc[nt][r] = (acc[nt][r]-mu)*rs;
  }

  __syncthreads();   // barrier #2: all waves done reading p2 -> [0..32K) reusable as out-tile

  // ---- branches: u = relu(xhat*gm + bm); LN3; relu; wave-local tile + copy ----
  for (int br = 0; br < 2; br++){
    float s3[4] = {0.f,0.f,0.f,0.f}, q3[4] = {0.f,0.f,0.f,0.f};
    #pragma unroll
    for (int nt=0; nt<16; nt++){
      int col = nt*16 + l15;
      float gm = SCf[(4*br)*256 + col], bm = SCf[(4*br+1)*256 + col];
      #pragma unroll
      for (int r=0; r<4; r++){
        float u = fmaxf(acc[nt][r]*gm + bm, 0.f);
        s3[r] += u; q3[r] += u*u;
      }
    }
    float m3[4], r3[4];
    #pragma unroll
    for (int r=0; r<4; r++){
      float s = s3[r], q = q3[r];
      #pragma unroll
      for (int m = 1; m < 16; m <<= 1){ s += __shfl_xor(s, m); q += __shfl_xor(q, m); }
      float mu = s*(1.f/256.f);
      m3[r] = mu; r3[r] = rsqrtf(q*(1.f/256.f) - mu*mu + 1e-5f);
    }
    #pragma unroll
    for (int nt=0; nt<16; nt++){
      int col = nt*16 + l15;
      float gm = SCf[(4*br)*256 + col], bm = SCf[(4*br+1)*256 + col];
      float g3 = SCf[(4*br+2)*256 + col], b3 = SCf[(4*br+3)*256 + col];
      #pragma unroll
      for (int r=0; r<4; r++){
        int row = 16*w + lg*4 + r;
        float u = fmaxf(acc[nt][r]*gm + bm, 0.f);
        float f = fmaxf((u - m3[r])*r3[r]*g3 + b3, 0.f);
        *(u16*)(lds + row*512 + ((2*col) ^ ((row&7)<<4))) = f2bf(f);
      }
    }
    // wave-local copy out (rows 16w..16w+15); same-wave DS ordering, no barrier
    {
      u16* outp = (br ? frin : fcin) + (size_t)b * KOUT;
      #pragma unroll
      for (int p = 0; p < 8; p++){
        int off = w*8192 + p*1024 + l*16;
        int row = off >> 9;
        if (row < Tc){
          int cb = off & 511;
          uint4 v = *(const uint4*)(lds + row*512 + (cb ^ ((row&7)<<4)));
          *(uint4*)((char*)outp + off) = v;
        }
      }
    }
  }
}

// ---------------- outGEMM partial (LDS-staged): pbuf[(z*8+sp)][4800][256] ----------------
__global__ __launch_bounds__(256, 4) void outgemm_part(
    const u16* __restrict__ fcin, const u16* __restrict__ frin,
    const u16* __restrict__ ocw, const u16* __restrict__ orw,
    float* __restrict__ pbuf)
{
  __shared__ u16 smA[64*64];
  __shared__ u16 smB[256*64];
  const int tid = threadIdx.x;
  const int z = blockIdx.y, sp = blockIdx.z;
  const int m0 = blockIdx.x * 64;
  const u16* A = z ? frin : fcin;
  const u16* W = z ? orw : ocw;
  const int l = tid & 63, w = tid >> 6, l15 = l & 15, lg = l >> 4;

  f32x4 acc[4][4];
  #pragma unroll
  for (int i=0;i<4;i++)
    #pragma unroll
    for (int j=0;j<4;j++) acc[i][j] = zero4();

  // 196 kt-tiles split 8 ways: [ (sp*49)>>1 , ((sp+1)*49)>>1 )
  const int kt0 = (sp*49) >> 1, kt1 = ((sp+1)*49) >> 1;
  for (int kt = kt0; kt < kt1; kt++){
    #pragma unroll
    for (int p = 0; p < 2; p++){
      int base = (w + p*4)*1024;
      int lin = base + l*16;
      int row = lin >> 7, cb = lin & 127;
      GLDS16((const char*)A + (size_t)(m0 + row)*25088 + kt*128 + (cb ^ ((row & 7) << 4)), (char*)smA + base);
    }
    #pragma unroll
    for (int p = 0; p < 8; p++){
      int base = (w + p*4)*1024;
      int lin = base + l*16;
      int n = lin >> 7, cb = lin & 127;
      GLDS16((const char*)W + (size_t)n*25088 + kt*128 + (cb ^ ((n & 7) << 4)), (char*)smB + base);
    }
    __syncthreads();
    #pragma unroll
    for (int ks = 0; ks < 2; ks++){
      bf16x8 av[4], bv[4];
      #pragma unroll
      for (int mt=0; mt<4; mt++){
        int row = mt*16 + l15;
        av[mt] = *(const bf16x8*)((const char*)smA + row*128 + ((ks*64 + lg*16) ^ ((row&7)<<4)));
      }
      #pragma unroll
      for (int nt=0; nt<4; nt++){
        int row = w*64 + nt*16 + l15;
        bv[nt] = *(const bf16x8*)((const char*)smB + row*128 + ((ks*64 + lg*16) ^ ((row&7)<<4)));
      }
      #pragma unroll
      for (int mt=0; mt<4; mt++)
        #pragma unroll
        for (int nt=0; nt<4; nt++)
          acc[mt][nt] = mfma16(av[mt], bv[nt], acc[mt][nt]);
    }
    __syncthreads();
  }
  float* pb = pbuf + ((size_t)(z*8 + sp)*Bc)*256;
  #pragma unroll
  for (int mt=0; mt<4; mt++)
    #pragma unroll
    for (int r=0; r<4; r++){
      int row = m0 + mt*16 + lg*4 + r;
      #pragma unroll
      for (int nt=0; nt<4; nt++)
        pb[(size_t)row*256 + w*64 + nt*16 + l15] = acc[mt][nt][r];
    }
}

// ---------------- LN4 finisher: sum 8 partials + bias, LN, relu -> fp32 out ----------------
__global__ __launch_bounds__(256) void ln4fin(const float* __restrict__ pbuf,
    const float* __restrict__ ocb, const float* __restrict__ orb,
    const float* __restrict__ n4cg, const float* __restrict__ n4cb,
    const float* __restrict__ n4rg, const float* __restrict__ n4rb,
    float* __restrict__ dout)
{
  int R = blockIdx.x*4 + (threadIdx.x >> 6);
  int z = R >= Bc;
  int box = R - z*Bc;
  int lane = threadIdx.x & 63;
  int col = lane*4;
  float4 v = make_float4(0.f,0.f,0.f,0.f);
  #pragma unroll
  for (int s = 0; s < 8; s++){
    float4 p = *(const float4*)(pbuf + ((size_t)(z*8 + s)*Bc + box)*256 + col);
    v.x += p.x; v.y += p.y; v.z += p.z; v.w += p.w;
  }
  float4 bi = *(const float4*)((z ? orb : ocb) + col);
  v.x += bi.x; v.y += bi.y; v.z += bi.z; v.w += bi.w;
  float s = v.x+v.y+v.z+v.w;
  float q = v.x*v.x+v.y*v.y+v.z*v.z+v.w*v.w;
  #pragma unroll
  for (int m = 1; m < 64; m <<= 1){ s += __shfl_xor(s, m); q += __shfl_xor(q, m); }
  float mu = s*(1.f/256.f);
  float rs = rsqrtf(q*(1.f/256.f) - mu*mu + 1e-5f);
  float4 g = *(const float4*)((z ? n4rg : n4cg) + col);
  float4 bb = *(const float4*)((z ? n4rb : n4cb) + col);
  float4 o;
  o.x = fmaxf((v.x-mu)*rs*g.x + bb.x, 0.f);
  o.y = fmaxf((v.y-mu)*rs*g.y + bb.y, 0.f);
  o.z = fmaxf((v.z-mu)*rs*g.z + bb.z, 0.f);
  o.w = fmaxf((v.w-mu)*rs*g.w + bb.w, 0.f);
  *(float4*)(dout + (size_t)z*OUTSTRIDE + (size_t)box*256 + col) = o;
}

extern "C" void kernel_launch(void* const* d_in, const int* in_sizes, int n_in,
                              void* d_out, int out_size, void* d_ws, size_t ws_size,
                              hipStream_t stream)
{
  (void)in_sizes; (void)n_in; (void)out_size;
  const float* pro  = (const float*)d_in[0];
  const float* roi  = (const float*)d_in[1];
  const float* dynw = (const float*)d_in[2];
  const float* dynb = (const float*)d_in[3];
  const float* n1g = (const float*)d_in[4];
  const float* n1b = (const float*)d_in[5];
  const float* n2g = (const float*)d_in[6];
  const float* n2b = (const float*)d_in[7];
  const float* pc1w = (const float*)d_in[8];
  const float* pc1b = (const float*)d_in[9];
  const float* pc2w = (const float*)d_in[10];
  const float* pc2b = (const float*)d_in[11];
  const float* n3cg = (const float*)d_in[12];
  const float* n3cb = (const float*)d_in[13];
  const float* pr1w = (const float*)d_in[14];
  const float* pr1b = (const float*)d_in[15];
  const float* pr2w = (const float*)d_in[16];
  const float* pr2b = (const float*)d_in[17];
  const float* n3rg = (const float*)d_in[18];
  const float* n3rb = (const float*)d_in[19];
  const float* ocw = (const float*)d_in[20];
  const float* ocb = (const float*)d_in[21];
  const float* n4cg = (const float*)d_in[22];
  const float* n4cb = (const float*)d_in[23];
  const float* orw = (const float*)d_in[24];
  const float* orb = (const float*)d_in[25];
  const float* n4rg = (const float*)d_in[26];
  const float* n4rb = (const float*)d_in[27];
  float* dout = (float*)d_out;

  char* ws = (char*)d_ws;
  size_t off = 0;
  auto alloc = [&](size_t bytes) -> char* {
    char* p = ws + off;
    off += (bytes + 255) & ~(size_t)255;
    return p;
  };
  u16* dynwB = (u16*)alloc((size_t)32768*256*2);
  float* dynbP = (float*)alloc((size_t)32768*4);
  u16* ocwB  = (u16*)alloc((size_t)12544*256*2);
  u16* orwB  = (u16*)alloc((size_t)12544*256*2);
  u16* proB  = (u16*)alloc((size_t)4992*256*2);
  float* mcls = (float*)alloc((size_t)4800*256*4);
  float* mreg = (float*)alloc((size_t)4800*256*4);
  u16* fcinF  = (u16*)alloc((size_t)Bc*25088);          // full 4800 boxes
  u16* frinF  = (u16*)alloc((size_t)Bc*25088);
  float* pbufF = (float*)alloc((size_t)16*Bc*256*4);    // 16 partials x 4800 x 256
  size_t fixedOff = off;

  // params chunk: keep L3-resident between gemm1 and conv
  int C = 480;
  const int copts[] = {1200, 960, 800, 600, 480};
  for (int i = 0; i < (int)(sizeof(copts)/sizeof(int)); i++){
    size_t need = fixedOff + (size_t)copts[i]*65536;
    if (need <= ws_size){ C = copts[i]; break; }
  }
  u16* paramsC = (u16*)alloc((size_t)C*65536);

  cvt_dynw_perm<<<1024, 256, 0, stream>>>(dynw, dynb, dynwB, dynbP);
  cvt_kernel<<<3136, 256, 0, stream>>>(ocw, ocwB, 12544*256);
  cvt_kernel<<<3136, 256, 0, stream>>>(orw, orwB, 12544*256);
  procvt_kernel<<<1248, 256, 0, stream>>>(pro, proB);
  masks_kernel<<<600, 256, 0, stream>>>(pro, pc1w, pc1b, pc2w, pc2b,
                                        pr1w, pr1b, pr2w, pr2b, mcls, mreg);
  int nch = (Bc + C - 1) / C;
  for (int c = 0; c < nch; c++){
    int b0 = c*C;
    int Cc = (b0 + C <= Bc) ? C : (Bc - b0);
    gemm1_kernel<<<dim3((Cc+127)/128, 256), 512, 0, stream>>>(proB, dynwB, dynbP, paramsC, b0, Cc);
    conv_kernel<<<Cc, 256, 0, stream>>>(roi, paramsC, n1g, n1b, n2g, n2b,
                                        n3cg, n3cb, n3rg, n3rb, mcls, mreg,
                                        fcinF, frinF, b0);
  }
  outgemm_part<<<dim3(75, 2, 8), 256, 0, stream>>>(fcinF, frinF, ocwB, orwB, pbufF);
  ln4fin<<<2400, 256, 0, stream>>>(pbufF, ocb, orb, n4cg, n4cb, n4rg, n4rb, dout);
}